// Round 12
// baseline (834.117 us; speedup 1.0000x reference)
//
#include <hip/hip_runtime.h>
#include <hip/hip_fp16.h>

typedef _Float16 f16;
typedef _Float16 f16x4 __attribute__((ext_vector_type(4)));
typedef _Float16 f16x8 __attribute__((ext_vector_type(8)));
typedef float f32x4 __attribute__((ext_vector_type(4)));

#define B_SZ   4096
#define T_SZ   32
#define VOCAB  10000
#define E_SZ   300
#define H_SZ   300
#define KP     320          // embT row width (10x32)
#define GP     304          // per-gate padded N (19x16)
#define G4     1216         // 4*GP
#define LDA    328          // hbuf row stride f16 (16B-aligned rows)
#define LDG    1224         // kR8 gates row stride f16
#define LDG2   1224         // interleaved gates row stride f16 ([j][4] + pad)

__device__ __forceinline__ float sigmoid_f(float x) {
    return 1.f / (1.f + __expf(-x));
}
__device__ __forceinline__ float tanh_f(float x) {
    // 2*sigmoid(2x)-1 : one exp, no clamp (v_exp_f32 saturates cleanly)
    return 2.f / (1.f + __expf(-2.f * x)) - 1.f;
}

// P0: embed_w f32 [V][300] -> embT f16 [V][320] zero-padded
__global__ void kP0(const float* __restrict__ ew, f16* __restrict__ embT) {
    int v = blockIdx.x, k = threadIdx.x;           // 320 threads
    embT[(size_t)v * KP + k] = (k < E_SZ) ? (f16)ew[(size_t)v * E_SZ + k] : (f16)0.f;
}

// kPW3: pack weights into MFMA-B-fragment order.
// Wpk: fused stream blocks (gate,nt,k20) for kX2/kR8.  WhhS: W_hh-only contiguous
// stream blocks (gate,nt,k10) for kR11.
__global__ void kPW3(const float* __restrict__ wih, const float* __restrict__ whh,
                     const float* __restrict__ bih, const float* __restrict__ bhh,
                     f16* __restrict__ Wpk, f16* __restrict__ WhhS,
                     float* __restrict__ biasp) {
    int bid = blockIdx.x;                          // 0..1519 = (gate*19+nt)*20+k
    int lane = threadIdx.x;                        // 64
    int k = bid % 20, ntg = bid / 20;
    int nt = ntg % 19, gate = ntg / 19;
    int c = lane & 15, q = lane >> 4;
    int j = nt * 16 + c;                           // 0..303
    int src = gate * H_SZ + j;
    f16 vals[8];
#pragma unroll
    for (int jj = 0; jj < 8; ++jj) {
        int kk = k * 32 + q * 8 + jj;
        float v = 0.f;
        if (j < H_SZ) {
            if (kk < KP) { if (kk < H_SZ) v = whh[(size_t)src * H_SZ + kk]; }
            else { int kx = kk - KP; if (kx < E_SZ) v = wih[(size_t)src * E_SZ + kx]; }
        }
        vals[jj] = (f16)v;
    }
    *(f16x8*)(Wpk + ((size_t)bid * 64 + lane) * 8) = *(const f16x8*)vals;
    if (k < 10)   // W_hh columns -> contiguous hh-only stream
        *(f16x8*)(WhhS + (((size_t)ntg * 10 + k) * 64 + lane) * 8) = *(const f16x8*)vals;
    if (k == 0 && q == 0)
        biasp[gate * GP + j] = (j < H_SZ) ? (bih[src] + bhh[src]) : 0.f;
}

// P2: weight-normed classifier W = g * v / ||v||  -> Wc f32 [2][GP]
__global__ void kP2(const float* __restrict__ cls_v, const float* __restrict__ cls_g,
                    float* __restrict__ Wc) {
    int lane = threadIdx.x;                        // 64
    for (int cl = 0; cl < 2; ++cl) {
        float s = 0.f;
        for (int j = lane; j < H_SZ; j += 64) { float v = cls_v[cl * H_SZ + j]; s += v * v; }
        for (int off = 32; off; off >>= 1) s += __shfl_down(s, off);
        float nrm = sqrtf(__shfl(s, 0));
        float scale = cls_g[cl] / nrm;
        for (int j = lane; j < H_SZ; j += 64) Wc[cl * GP + j] = cls_v[cl * H_SZ + j] * scale;
    }
}

// kX2: per-vocab x-gate preacts, gate-interleaved f16:
// embX[v][j][gate] = (W_ih . emb[v] + b_ih + b_hh)[gate*300+j]
__global__ __launch_bounds__(512, 2)
void kX2(const f16* __restrict__ embT, const f16* __restrict__ Wpk,
         const float* __restrict__ biasp, f16* __restrict__ embX) {
    int tid = threadIdx.x;
    int v0 = blockIdx.x * 16;
    int wave = tid >> 6, lane = tid & 63;
    int c = lane & 15, q = lane >> 4;
    int gate = wave >> 1, half = wave & 1;
    int nt0 = half * 10, ntiles = half ? 9 : 10;   // 19 = 10 + 9
    const f16* wp0 = Wpk + (((size_t)(gate * 19 + nt0) * 20 + 10) * 64 + lane) * 8;
    f16x8 afr[10];
    const f16* arow = embT + (size_t)(v0 + c) * KP + q * 8;
#pragma unroll
    for (int k = 0; k < 10; ++k)
        afr[k] = *(const f16x8*)(arow + k * 32);
    f16x8 buf[10];
#pragma unroll
    for (int s = 0; s < 10; ++s)
        buf[s] = *(const f16x8*)(wp0 + (size_t)s * 512);
#pragma unroll 1
    for (int nt = 0; nt < ntiles - 1; ++nt) {
        int jcol = (nt0 + nt) * 16 + c;
        float bia = biasp[gate * GP + jcol];
        f32x4 acc = {bia, bia, bia, bia};
#pragma unroll
        for (int k = 0; k < 10; ++k) {
            acc = __builtin_amdgcn_mfma_f32_16x16x32_f16(afr[k], buf[k], acc, 0, 0, 0);
            buf[k] = *(const f16x8*)(wp0 + (size_t)(nt * 20 + k + 20) * 512);
        }
#pragma unroll
        for (int r = 0; r < 4; ++r)
            embX[((size_t)(v0 + q * 4 + r) * GP + jcol) * 4 + gate] = (f16)acc[r];
    }
    {
        int nt = ntiles - 1;
        int jcol = (nt0 + nt) * 16 + c;
        float bia = biasp[gate * GP + jcol];
        f32x4 acc = {bia, bia, bia, bia};
#pragma unroll
        for (int k = 0; k < 10; ++k)
            acc = __builtin_amdgcn_mfma_f32_16x16x32_f16(afr[k], buf[k], acc, 0, 0, 0);
#pragma unroll
        for (int r = 0; r < 4; ++r)
            embX[((size_t)(v0 + q * 4 + r) * GP + jcol) * 4 + gate] = (f16)acc[r];
    }
}

// kR11: W_hh-only recurrence, 128 blocks x 512 thr (8 waves), 32 rows/block.
// Wave (gate, half) with TM=2: every weight B-fragment feeds 2 MFMAs (m-tiles
// rows 0-15 and 16-31) -> total L2 weight traffic HALVED vs 256-block layout
// (which was at the ~2.7 TB/s/XCD L2-broadcast ceiling).
__global__ __launch_bounds__(512, 2)
void kR11(const int* __restrict__ cap,
          const int* __restrict__ cap_len,
          const f16* __restrict__ embX,
          const f16* __restrict__ WhhS,
          float* __restrict__ hlast) {
    extern __shared__ __align__(16) char smem[];
    f16*   hbuf   = (f16*)smem;                         // 32*328*2  = 20992
    f16*   gatesI = (f16*)(smem + 20992);               // 32*1224*2 = 78336
    float* cbuf   = (float*)(smem + 20992 + 78336);     // 32*320*4  = 40960
    int*   capv   = (int*)(smem + 20992 + 78336 + 40960);   // 32*32*4 = 4096
    int*   lens   = (int*)(smem + 20992 + 78336 + 40960 + 4096); // 128
    int tid = threadIdx.x;
    int b0 = blockIdx.x * 32;
    if (tid < 32) lens[tid] = cap_len[b0 + tid];
    for (int i = tid; i < 32 * T_SZ; i += 512) capv[i] = cap[(size_t)b0 * T_SZ + i];
    for (int i = tid; i < 32 * LDA; i += 512) hbuf[i] = (f16)0.f;  // pads stay 0
    for (int i = tid; i < 32 * 320; i += 512) cbuf[i] = 0.f;
    __syncthreads();
    int wave = tid >> 6, lane = tid & 63;
    int c = lane & 15, q = lane >> 4;
    int gate = wave >> 1, half = wave & 1;
    int nt0 = half * 10, ntiles = half ? 9 : 10;   // 19 = 10 + 9
    const f16* wp0 = WhhS + ((size_t)((gate * 19 + nt0) * 10) * 64 + lane) * 8;
    const f16* hrow0 = hbuf + c * LDA + q * 8;          // m-tile 0 (rows 0-15)
    const f16* hrow1 = hbuf + (16 + c) * LDA + q * 8;   // m-tile 1 (rows 16-31)

    for (int t = 0; t < T_SZ; ++t) {
        // --- phase 1: h-preacts for both m-tiles, B-frags reused x2 ---
        f16x8 buf[10];
#pragma unroll
        for (int s = 0; s < 10; ++s)
            buf[s] = *(const f16x8*)(wp0 + (size_t)s * 512);
        f16x8 afr0[10];
#pragma unroll
        for (int k = 0; k < 10; ++k)
            afr0[k] = *(const f16x8*)(hrow0 + k * 32);
#pragma unroll 1
        for (int nt = 0; nt < ntiles; ++nt) {
            int jcol = (nt0 + nt) * 16 + c;
            f32x4 acc0 = {0.f, 0.f, 0.f, 0.f};
            f32x4 acc1 = {0.f, 0.f, 0.f, 0.f};
            bool more = (nt + 1 < ntiles);
#pragma unroll
            for (int k = 0; k < 10; ++k) {
                f16x8 a1 = *(const f16x8*)(hrow1 + k * 32);
                acc0 = __builtin_amdgcn_mfma_f32_16x16x32_f16(afr0[k], buf[k], acc0, 0, 0, 0);
                acc1 = __builtin_amdgcn_mfma_f32_16x16x32_f16(a1,      buf[k], acc1, 0, 0, 0);
                if (more)
                    buf[k] = *(const f16x8*)(wp0 + (size_t)(nt * 10 + k + 10) * 512);
            }
#pragma unroll
            for (int r = 0; r < 4; ++r) {
                gatesI[(q * 4 + r) * LDG2 + jcol * 4 + gate]        = (f16)acc0[r];
                gatesI[(16 + q * 4 + r) * LDG2 + jcol * 4 + gate]   = (f16)acc1[r];
            }
        }
        __syncthreads();
        // --- phase 2: cell update; x-preacts = one f16x4 per element ---
#pragma unroll
        for (int it = 0; it < 20; ++it) {
            int idx = tid + it * 512;              // 0..10239 = 32*320
            int m = idx / 320, j = idx - m * 320;
            if (j < H_SZ) {
                int v = capv[m * T_SZ + t];
                f16x4 xi = *(const f16x4*)(embX + ((size_t)v * GP + j) * 4);
                f16x4 hi = *(const f16x4*)(&gatesI[m * LDG2 + j * 4]);
                float gi = (float)hi[0] + (float)xi[0];
                float gf = (float)hi[1] + (float)xi[1];
                float gg = (float)hi[2] + (float)xi[2];
                float go = (float)hi[3] + (float)xi[3];
                float ii = sigmoid_f(gi);
                float ff = sigmoid_f(gf);
                float gt = tanh_f(gg);
                float oo = sigmoid_f(go);
                float cn = ff * cbuf[idx] + ii * gt;
                cbuf[idx] = cn;
                float hh = oo * tanh_f(cn);
                hbuf[m * LDA + j] = (f16)hh;
                if (t == lens[m] - 1) hlast[(size_t)(b0 + m) * GP + j] = hh;
            }
        }
        __syncthreads();
    }
}

// kR8 (fallback, proven): fused [h|x] recurrence for small-ws runs.
__global__ __launch_bounds__(512, 2)
void kR8(const int* __restrict__ cap,
         const int* __restrict__ cap_len,
         const f16* __restrict__ embT,
         const f16* __restrict__ Wpk,
         const float* __restrict__ biasp,
         float* __restrict__ hlast) {
    extern __shared__ __align__(16) char smem[];
    f16*   hbuf  = (f16*)smem;                          // 10496
    f16*   xbuf  = (f16*)(smem + 10496);                // 10496
    f16*   gates = (f16*)(smem + 20992);                // 39168
    float* biasL = (float*)(smem + 60160);              // 4864
    int*   capv  = (int*)(smem + 65024);                // 2048
    int*   lens  = (int*)(smem + 67072);                // 64
    int tid = threadIdx.x;
    int b0 = blockIdx.x * 16;
    if (tid < 16) lens[tid] = cap_len[b0 + tid];
    for (int i = tid; i < 16 * T_SZ; i += 512) capv[i] = cap[(size_t)b0 * T_SZ + i];
    for (int i = tid; i < 16 * LDA; i += 512) hbuf[i] = (f16)0.f;
    for (int i = tid; i < G4; i += 512) biasL[i] = biasp[i];
    __syncthreads();
    for (int i = tid; i < 16 * 40; i += 512) {
        int m = i / 40, c8 = i - m * 40;
        int v = capv[m * T_SZ + 0];
        *(f16x8*)(xbuf + m * LDA + c8 * 8) = *(const f16x8*)(embT + (size_t)v * KP + c8 * 8);
    }
    __syncthreads();
    int wave = tid >> 6, lane = tid & 63;
    int c = lane & 15, q = lane >> 4;
    int gate = wave >> 1, half = wave & 1;
    int nt0 = half * 10, ntiles = half ? 9 : 10;
    const f16* wp0 = Wpk + ((size_t)((gate * 19 + nt0) * 20) * 64 + lane) * 8;
    const f16* hrow = hbuf + c * LDA + q * 8;
    const f16* xrow = xbuf + c * LDA + q * 8;
    float creg[10];
#pragma unroll
    for (int i = 0; i < 10; ++i) creg[i] = 0.f;

    for (int t = 0; t < T_SZ; ++t) {
        f16x8 afr[10];
#pragma unroll
        for (int k = 0; k < 10; ++k)
            afr[k] = *(const f16x8*)(hrow + k * 32);
        f16x8 buf[10];
#pragma unroll
        for (int s = 0; s < 10; ++s)
            buf[s] = *(const f16x8*)(wp0 + (size_t)s * 512);
#pragma unroll 1
        for (int nt = 0; nt < ntiles - 1; ++nt) {
            int base = nt * 20;
            int ncol = gate * GP + (nt0 + nt) * 16 + c;
            float bia = biasL[ncol];
            f32x4 acch = {bia, bia, bia, bia};
            f32x4 accx = {0.f, 0.f, 0.f, 0.f};
#pragma unroll
            for (int k = 0; k < 20; ++k) {
                if (k < 10) {
                    acch = __builtin_amdgcn_mfma_f32_16x16x32_f16(afr[k], buf[k % 10], acch, 0, 0, 0);
                } else {
                    f16x8 a = *(const f16x8*)(xrow + (k - 10) * 32);
                    accx = __builtin_amdgcn_mfma_f32_16x16x32_f16(a, buf[k % 10], accx, 0, 0, 0);
                }
                buf[k % 10] = *(const f16x8*)(wp0 + (size_t)(base + k + 10) * 512);
            }
#pragma unroll
            for (int r = 0; r < 4; ++r)
                gates[(q * 4 + r) * LDG + ncol] = (f16)(acch[r] + accx[r]);
        }
        {
            int nt = ntiles - 1;
            int base = nt * 20;
            int ncol = gate * GP + (nt0 + nt) * 16 + c;
            float bia = biasL[ncol];
            f32x4 acch = {bia, bia, bia, bia};
            f32x4 accx = {0.f, 0.f, 0.f, 0.f};
#pragma unroll
            for (int k = 0; k < 20; ++k) {
                if (k < 10) {
                    acch = __builtin_amdgcn_mfma_f32_16x16x32_f16(afr[k], buf[k % 10], acch, 0, 0, 0);
                    buf[k % 10] = *(const f16x8*)(wp0 + (size_t)(base + k + 10) * 512);
                } else {
                    f16x8 a = *(const f16x8*)(xrow + (k - 10) * 32);
                    accx = __builtin_amdgcn_mfma_f32_16x16x32_f16(a, buf[k % 10], accx, 0, 0, 0);
                }
            }
#pragma unroll
            for (int r = 0; r < 4; ++r)
                gates[(q * 4 + r) * LDG + ncol] = (f16)(acch[r] + accx[r]);
        }
        __syncthreads();
        int tp1 = t + 1;
        if (tp1 < T_SZ) {
            for (int i = tid; i < 16 * 40; i += 512) {
                int m = i / 40, c8 = i - m * 40;
                int v = capv[m * T_SZ + tp1];
                *(f16x8*)(xbuf + m * LDA + c8 * 8) =
                    *(const f16x8*)(embT + (size_t)v * KP + c8 * 8);
            }
        }
#pragma unroll
        for (int it = 0; it < 10; ++it) {
            int idx = tid + it * 512;
            int m = idx / 320, j = idx - m * 320;
            if (j < H_SZ) {
                const f16* gr = gates + m * LDG;
                float gi = (float)gr[j];
                float gf = (float)gr[GP + j];
                float gg = (float)gr[2 * GP + j];
                float go = (float)gr[3 * GP + j];
                float ii = sigmoid_f(gi);
                float ff = sigmoid_f(gf);
                float gt = tanh_f(gg);
                float oo = sigmoid_f(go);
                float cn = ff * creg[it] + ii * gt;
                creg[it] = cn;
                float hh = oo * tanh_f(cn);
                hbuf[m * LDA + j] = (f16)hh;
                if (t == lens[m] - 1) hlast[(size_t)(b0 + m) * GP + j] = hh;
            }
        }
        __syncthreads();
    }
}

// kC: out[row][cl] = hlast[row] . Wc[cl] + cls_b[cl]
__global__ void kC(const float* __restrict__ hlast, const float* __restrict__ Wc,
                   const float* __restrict__ cls_b, float* __restrict__ out) {
    int row = blockIdx.x, lane = threadIdx.x;      // 64 threads
    const float* h = hlast + (size_t)row * GP;
    float s0 = 0.f, s1 = 0.f;
    for (int j = lane; j < H_SZ; j += 64) {
        float hv = h[j];
        s0 += hv * Wc[j];
        s1 += hv * Wc[GP + j];
    }
    for (int off = 32; off; off >>= 1) {
        s0 += __shfl_down(s0, off);
        s1 += __shfl_down(s1, off);
    }
    if (lane == 0) {
        out[row * 2 + 0] = s0 + cls_b[0];
        out[row * 2 + 1] = s1 + cls_b[1];
    }
}

extern "C" void kernel_launch(void* const* d_in, const int* in_sizes, int n_in,
                              void* d_out, int out_size, void* d_ws, size_t ws_size,
                              hipStream_t stream) {
    const int*   cap     = (const int*)d_in[0];
    const int*   cap_len = (const int*)d_in[1];
    const float* embed_w = (const float*)d_in[2];
    const float* W_ih    = (const float*)d_in[3];
    const float* W_hh    = (const float*)d_in[4];
    const float* b_ih    = (const float*)d_in[5];
    const float* b_hh    = (const float*)d_in[6];
    const float* cls_v   = (const float*)d_in[7];
    const float* cls_g   = (const float*)d_in[8];
    const float* cls_b   = (const float*)d_in[9];
    float* out = (float*)d_out;

    char* w = (char*)d_ws;
    size_t off = 0;
    auto alloc = [&](size_t bytes) -> void* {
        void* p = w + off;
        off += (bytes + 255) & ~(size_t)255;
        return p;
    };
    f16*   embT  = (f16*)alloc((size_t)VOCAB * KP * sizeof(f16));      // 6.4 MB
    f16*   Wpk   = (f16*)alloc((size_t)1520 * 64 * 8 * sizeof(f16));   // 1.56 MB
    f16*   WhhS  = (f16*)alloc((size_t)760 * 64 * 8 * sizeof(f16));    // 778 KB
    float* biasp = (float*)alloc((size_t)G4 * sizeof(float));
    float* Wc    = (float*)alloc((size_t)2 * GP * sizeof(float));
    float* hlast = (float*)alloc((size_t)B_SZ * GP * sizeof(float));   // 5.0 MB
    f16*   embX  = (f16*)(w + off);                                    // 24.3 MB f16 [V][GP][4]
    size_t need_split = off + ((size_t)VOCAB * GP * 4 * sizeof(f16) + 255);
    bool split = (ws_size >= need_split);          // deterministic per run

    kP0<<<VOCAB, KP, 0, stream>>>(embed_w, embT);
    kPW3<<<1520, 64, 0, stream>>>(W_ih, W_hh, b_ih, b_hh, Wpk, WhhS, biasp);
    kP2<<<1, 64, 0, stream>>>(cls_v, cls_g, Wc);
    if (split) {
        // dynamic LDS 144,512 B (<= 160 KB/CU); host-side config, capture-safe
        static const int smem_r11 = 20992 + 78336 + 40960 + 4096 + 128;
        (void)hipFuncSetAttribute((const void*)kR11,
                                  hipFuncAttributeMaxDynamicSharedMemorySize, smem_r11);
        kX2<<<VOCAB / 16, 512, 0, stream>>>(embT, Wpk, biasp, embX);
        kR11<<<B_SZ / 32, 512, smem_r11, stream>>>(cap, cap_len, embX, WhhS, hlast);
    } else {
        static const int smem_r8 = 67072 + 64;
        (void)hipFuncSetAttribute((const void*)kR8,
                                  hipFuncAttributeMaxDynamicSharedMemorySize, smem_r8);
        kR8<<<B_SZ / 16, 512, smem_r8, stream>>>(cap, cap_len, embT, Wpk, biasp, hlast);
    }
    kC<<<B_SZ, 64, 0, stream>>>(hlast, Wc, cls_b, out);
}

// Round 13
// 507.521 us; speedup vs baseline: 1.6435x; 1.6435x over previous
//
#include <hip/hip_runtime.h>
#include <hip/hip_fp16.h>

typedef _Float16 f16;
typedef _Float16 f16x4 __attribute__((ext_vector_type(4)));
typedef _Float16 f16x8 __attribute__((ext_vector_type(8)));
typedef float f32x4 __attribute__((ext_vector_type(4)));

#define B_SZ   4096
#define T_SZ   32
#define VOCAB  10000
#define E_SZ   300
#define H_SZ   300
#define KP     320          // embT row width (10x32)
#define GP     304          // per-gate padded N (19x16)
#define G4     1216         // 4*GP
#define LDA    328          // hbuf row stride f16 (16B-aligned rows)
#define LDG    1224         // kR8 gates row stride f16
#define LDC    308          // cbuf row stride f32
#define ROWS   16
#define NBLK   (B_SZ/ROWS)  // 256 blocks -> 1 per CU

__device__ __forceinline__ float sigmoid_f(float x) {
    return 1.f / (1.f + __expf(-x));
}
__device__ __forceinline__ float tanh_f(float x) {
    return 2.f / (1.f + __expf(-2.f * x)) - 1.f;
}

// P0: embed_w f32 [V][300] -> embT f16 [V][320] zero-padded
__global__ void kP0(const float* __restrict__ ew, f16* __restrict__ embT) {
    int v = blockIdx.x, k = threadIdx.x;           // 320 threads
    embT[(size_t)v * KP + k] = (k < E_SZ) ? (f16)ew[(size_t)v * E_SZ + k] : (f16)0.f;
}

// kPW2: fused-stream packing (for kX2 / kR8): block (gate,nt,k20), 1 KB each.
__global__ void kPW2(const float* __restrict__ wih, const float* __restrict__ whh,
                     const float* __restrict__ bih, const float* __restrict__ bhh,
                     f16* __restrict__ Wpk, float* __restrict__ biasp) {
    int bid = blockIdx.x;                          // 0..1519 = (gate*19+nt)*20+k
    int lane = threadIdx.x;                        // 64
    int k = bid % 20, ntg = bid / 20;
    int nt = ntg % 19, gate = ntg / 19;
    int c = lane & 15, q = lane >> 4;
    int j = nt * 16 + c;
    int src = gate * H_SZ + j;
    f16 vals[8];
#pragma unroll
    for (int jj = 0; jj < 8; ++jj) {
        int kk = k * 32 + q * 8 + jj;
        float v = 0.f;
        if (j < H_SZ) {
            if (kk < KP) { if (kk < H_SZ) v = whh[(size_t)src * H_SZ + kk]; }
            else { int kx = kk - KP; if (kx < E_SZ) v = wih[(size_t)src * E_SZ + kx]; }
        }
        vals[jj] = (f16)v;
    }
    *(f16x8*)(Wpk + ((size_t)bid * 64 + lane) * 8) = *(const f16x8*)vals;
    if (k == 0 && q == 0)
        biasp[gate * GP + j] = (j < H_SZ) ? (bih[src] + bhh[src]) : 0.f;
}

// kPW4: gate-major W_hh-only packing for kR12: block (nt, gate, k10), 1 KB each.
// 800 blocks (760 real + 40 zero slack for unconditional prefetch).
__global__ void kPW4(const float* __restrict__ whh, f16* __restrict__ WgS) {
    int bid = blockIdx.x;                          // 0..799
    int lane = threadIdx.x;
    int c = lane & 15, q = lane >> 4;
    f16 vals[8];
    if (bid < 760) {
        int nt = bid / 40, g = (bid % 40) / 10, k = bid % 10;
        int j = nt * 16 + c;
        int src = g * H_SZ + j;
#pragma unroll
        for (int jj = 0; jj < 8; ++jj) {
            int kk = k * 32 + q * 8 + jj;
            float v = (j < H_SZ && kk < H_SZ) ? whh[(size_t)src * H_SZ + kk] : 0.f;
            vals[jj] = (f16)v;
        }
    } else {
#pragma unroll
        for (int jj = 0; jj < 8; ++jj) vals[jj] = (f16)0.f;
    }
    *(f16x8*)(WgS + ((size_t)bid * 64 + lane) * 8) = *(const f16x8*)vals;
}

// P2: weight-normed classifier W = g * v / ||v||  -> Wc f32 [2][GP]
__global__ void kP2(const float* __restrict__ cls_v, const float* __restrict__ cls_g,
                    float* __restrict__ Wc) {
    int lane = threadIdx.x;
    for (int cl = 0; cl < 2; ++cl) {
        float s = 0.f;
        for (int j = lane; j < H_SZ; j += 64) { float v = cls_v[cl * H_SZ + j]; s += v * v; }
        for (int off = 32; off; off >>= 1) s += __shfl_down(s, off);
        float nrm = sqrtf(__shfl(s, 0));
        float scale = cls_g[cl] / nrm;
        for (int j = lane; j < H_SZ; j += 64) Wc[cl * GP + j] = cls_v[cl * H_SZ + j] * scale;
    }
}

// kX2: per-vocab x-gate preacts, gate-interleaved f16:
// embX[v][j][gate] = (W_ih . emb[v] + b_ih + b_hh)[gate*300+j]
__global__ __launch_bounds__(512, 2)
void kX2(const f16* __restrict__ embT, const f16* __restrict__ Wpk,
         const float* __restrict__ biasp, f16* __restrict__ embX) {
    int tid = threadIdx.x;
    int v0 = blockIdx.x * 16;
    int wave = tid >> 6, lane = tid & 63;
    int c = lane & 15, q = lane >> 4;
    int gate = wave >> 1, half = wave & 1;
    int nt0 = half * 10, ntiles = half ? 9 : 10;
    const f16* wp0 = Wpk + (((size_t)(gate * 19 + nt0) * 20 + 10) * 64 + lane) * 8;
    f16x8 afr[10];
    const f16* arow = embT + (size_t)(v0 + c) * KP + q * 8;
#pragma unroll
    for (int k = 0; k < 10; ++k)
        afr[k] = *(const f16x8*)(arow + k * 32);
    f16x8 buf[10];
#pragma unroll
    for (int s = 0; s < 10; ++s)
        buf[s] = *(const f16x8*)(wp0 + (size_t)s * 512);
#pragma unroll 1
    for (int nt = 0; nt < ntiles - 1; ++nt) {
        int jcol = (nt0 + nt) * 16 + c;
        float bia = biasp[gate * GP + jcol];
        f32x4 acc = {bia, bia, bia, bia};
#pragma unroll
        for (int k = 0; k < 10; ++k) {
            acc = __builtin_amdgcn_mfma_f32_16x16x32_f16(afr[k], buf[k], acc, 0, 0, 0);
            buf[k] = *(const f16x8*)(wp0 + (size_t)(nt * 20 + k + 20) * 512);
        }
#pragma unroll
        for (int r = 0; r < 4; ++r)
            embX[((size_t)(v0 + q * 4 + r) * GP + jcol) * 4 + gate] = (f16)acc[r];
    }
    {
        int nt = ntiles - 1;
        int jcol = (nt0 + nt) * 16 + c;
        float bia = biasp[gate * GP + jcol];
        f32x4 acc = {bia, bia, bia, bia};
#pragma unroll
        for (int k = 0; k < 10; ++k)
            acc = __builtin_amdgcn_mfma_f32_16x16x32_f16(afr[k], buf[k], acc, 0, 0, 0);
#pragma unroll
        for (int r = 0; r < 4; ++r)
            embX[((size_t)(v0 + q * 4 + r) * GP + jcol) * 4 + gate] = (f16)acc[r];
    }
}

// kR12: barrier-light recurrence. 256 blocks x 512 thr (8 waves), 16 rows.
// Wave w owns 2-3 j-tiles and computes ALL FOUR gate preacts in registers
// (gate-major weight stream), then does the cell update for its columns inline:
// gates never touch LDS, ONE barrier per step, double-buffered h.
__global__ __launch_bounds__(512, 2)
void kR12(const int* __restrict__ cap,
          const int* __restrict__ cap_len,
          const f16* __restrict__ embX,
          const f16* __restrict__ WgS,
          float* __restrict__ hlast) {
    __shared__ __align__(16) f16 hbuf[2][ROWS * LDA];   // 2 x 10496 B
    __shared__ float cbuf[ROWS * LDC];                  // 19712 B
    __shared__ int capv[ROWS * T_SZ];                   // 2048 B
    __shared__ int lens[ROWS];
    int tid = threadIdx.x;
    int b0 = blockIdx.x * ROWS;
    if (tid < ROWS) lens[tid] = cap_len[b0 + tid];
    for (int i = tid; i < ROWS * T_SZ; i += 512) capv[i] = cap[(size_t)b0 * T_SZ + i];
    for (int i = tid; i < 2 * ROWS * LDA; i += 512) ((f16*)hbuf)[i] = (f16)0.f;
    for (int i = tid; i < ROWS * LDC; i += 512) cbuf[i] = 0.f;
    __syncthreads();
    int wave = tid >> 6, lane = tid & 63;
    int c = lane & 15, q = lane >> 4;
    int tstart = (wave < 5) ? 2 * wave : 10 + 3 * (wave - 5);   // 19 = 5x2 + 3x3
    int tcnt   = (wave < 5) ? 2 : 3;
    const f16* wp0 = WgS + ((size_t)(tstart * 40) * 64 + lane) * 8;
    int tstop[4];
#pragma unroll
    for (int r = 0; r < 4; ++r) tstop[r] = lens[q * 4 + r] - 1;
    int cur = 0;

    for (int t = 0; t < T_SZ; ++t) {
        const f16* hb = hbuf[cur];
        f16*       hn = hbuf[cur ^ 1];
        f16x8 afr[10];
#pragma unroll
        for (int k = 0; k < 10; ++k)
            afr[k] = *(const f16x8*)(hb + c * LDA + k * 32 + q * 8);
        int vrow[4];
#pragma unroll
        for (int r = 0; r < 4; ++r) vrow[r] = capv[(q * 4 + r) * T_SZ + t];
        f16x8 buf[10];
#pragma unroll
        for (int s = 0; s < 10; ++s)
            buf[s] = *(const f16x8*)(wp0 + (size_t)s * 512);
#pragma unroll 1
        for (int nt = 0; nt < tcnt; ++nt) {
            int col = (tstart + nt) * 16 + c;
            const f16* wnext = wp0 + (size_t)(nt * 40) * 512;
            f32x4 acc0 = {0.f, 0.f, 0.f, 0.f};
            f32x4 acc1 = {0.f, 0.f, 0.f, 0.f};
            f32x4 acc2 = {0.f, 0.f, 0.f, 0.f};
            f32x4 acc3 = {0.f, 0.f, 0.f, 0.f};
#pragma unroll
            for (int k = 0; k < 10; ++k) {          // gate 0, prefetch gate 1
                acc0 = __builtin_amdgcn_mfma_f32_16x16x32_f16(afr[k], buf[k], acc0, 0, 0, 0);
                buf[k] = *(const f16x8*)(wnext + (size_t)(10 + k) * 512);
            }
#pragma unroll
            for (int k = 0; k < 10; ++k) {          // gate 1, prefetch gate 2
                acc1 = __builtin_amdgcn_mfma_f32_16x16x32_f16(afr[k], buf[k], acc1, 0, 0, 0);
                buf[k] = *(const f16x8*)(wnext + (size_t)(20 + k) * 512);
            }
#pragma unroll
            for (int k = 0; k < 10; ++k) {          // gate 2, prefetch gate 3
                acc2 = __builtin_amdgcn_mfma_f32_16x16x32_f16(afr[k], buf[k], acc2, 0, 0, 0);
                buf[k] = *(const f16x8*)(wnext + (size_t)(30 + k) * 512);
            }
#pragma unroll
            for (int k = 0; k < 10; ++k) {          // gate 3, prefetch next tile g0 (slack-safe)
                acc3 = __builtin_amdgcn_mfma_f32_16x16x32_f16(afr[k], buf[k], acc3, 0, 0, 0);
                buf[k] = *(const f16x8*)(wnext + (size_t)(40 + k) * 512);
            }
            // cell update for this tile: rows q*4+r, column col — gates stay in regs
#pragma unroll
            for (int r = 0; r < 4; ++r) {
                int row = q * 4 + r;
                f16x4 xi = *(const f16x4*)(embX + ((size_t)vrow[r] * GP + col) * 4);
                float gi = acc0[r] + (float)xi[0];
                float gf = acc1[r] + (float)xi[1];
                float gg = acc2[r] + (float)xi[2];
                float go = acc3[r] + (float)xi[3];
                float ii = sigmoid_f(gi);
                float ff = sigmoid_f(gf);
                float gt = tanh_f(gg);
                float oo = sigmoid_f(go);
                int ci = row * LDC + col;
                float cn = ff * cbuf[ci] + ii * gt;
                cbuf[ci] = cn;
                float hh = oo * tanh_f(cn);
                hn[row * LDA + col] = (f16)hh;
                if (t == tstop[r]) hlast[(size_t)(b0 + row) * GP + col] = hh;
            }
        }
        __syncthreads();
        cur ^= 1;
    }
}

// kR8 (fallback, proven): fused [h|x] recurrence for small-ws runs.
__global__ __launch_bounds__(512, 2)
void kR8(const int* __restrict__ cap,
         const int* __restrict__ cap_len,
         const f16* __restrict__ embT,
         const f16* __restrict__ Wpk,
         const float* __restrict__ biasp,
         float* __restrict__ hlast) {
    extern __shared__ __align__(16) char smem[];
    f16*   hbuf  = (f16*)smem;                          // 10496
    f16*   xbuf  = (f16*)(smem + 10496);                // 10496
    f16*   gates = (f16*)(smem + 20992);                // 39168
    float* biasL = (float*)(smem + 60160);              // 4864
    int*   capv  = (int*)(smem + 65024);                // 2048
    int*   lens  = (int*)(smem + 67072);                // 64
    int tid = threadIdx.x;
    int b0 = blockIdx.x * 16;
    if (tid < 16) lens[tid] = cap_len[b0 + tid];
    for (int i = tid; i < 16 * T_SZ; i += 512) capv[i] = cap[(size_t)b0 * T_SZ + i];
    for (int i = tid; i < 16 * LDA; i += 512) hbuf[i] = (f16)0.f;
    for (int i = tid; i < G4; i += 512) biasL[i] = biasp[i];
    __syncthreads();
    for (int i = tid; i < 16 * 40; i += 512) {
        int m = i / 40, c8 = i - m * 40;
        int v = capv[m * T_SZ + 0];
        *(f16x8*)(xbuf + m * LDA + c8 * 8) = *(const f16x8*)(embT + (size_t)v * KP + c8 * 8);
    }
    __syncthreads();
    int wave = tid >> 6, lane = tid & 63;
    int c = lane & 15, q = lane >> 4;
    int gate = wave >> 1, half = wave & 1;
    int nt0 = half * 10, ntiles = half ? 9 : 10;
    const f16* wp0 = Wpk + ((size_t)((gate * 19 + nt0) * 20) * 64 + lane) * 8;
    const f16* hrow = hbuf + c * LDA + q * 8;
    const f16* xrow = xbuf + c * LDA + q * 8;
    float creg[10];
#pragma unroll
    for (int i = 0; i < 10; ++i) creg[i] = 0.f;

    for (int t = 0; t < T_SZ; ++t) {
        f16x8 afr[10];
#pragma unroll
        for (int k = 0; k < 10; ++k)
            afr[k] = *(const f16x8*)(hrow + k * 32);
        f16x8 buf[10];
#pragma unroll
        for (int s = 0; s < 10; ++s)
            buf[s] = *(const f16x8*)(wp0 + (size_t)s * 512);
#pragma unroll 1
        for (int nt = 0; nt < ntiles - 1; ++nt) {
            int base = nt * 20;
            int ncol = gate * GP + (nt0 + nt) * 16 + c;
            float bia = biasL[ncol];
            f32x4 acch = {bia, bia, bia, bia};
            f32x4 accx = {0.f, 0.f, 0.f, 0.f};
#pragma unroll
            for (int k = 0; k < 20; ++k) {
                if (k < 10) {
                    acch = __builtin_amdgcn_mfma_f32_16x16x32_f16(afr[k], buf[k % 10], acch, 0, 0, 0);
                } else {
                    f16x8 a = *(const f16x8*)(xrow + (k - 10) * 32);
                    accx = __builtin_amdgcn_mfma_f32_16x16x32_f16(a, buf[k % 10], accx, 0, 0, 0);
                }
                buf[k % 10] = *(const f16x8*)(wp0 + (size_t)(base + k + 10) * 512);
            }
#pragma unroll
            for (int r = 0; r < 4; ++r)
                gates[(q * 4 + r) * LDG + ncol] = (f16)(acch[r] + accx[r]);
        }
        {
            int nt = ntiles - 1;
            int base = nt * 20;
            int ncol = gate * GP + (nt0 + nt) * 16 + c;
            float bia = biasL[ncol];
            f32x4 acch = {bia, bia, bia, bia};
            f32x4 accx = {0.f, 0.f, 0.f, 0.f};
#pragma unroll
            for (int k = 0; k < 20; ++k) {
                if (k < 10) {
                    acch = __builtin_amdgcn_mfma_f32_16x16x32_f16(afr[k], buf[k % 10], acch, 0, 0, 0);
                    buf[k % 10] = *(const f16x8*)(wp0 + (size_t)(base + k + 10) * 512);
                } else {
                    f16x8 a = *(const f16x8*)(xrow + (k - 10) * 32);
                    accx = __builtin_amdgcn_mfma_f32_16x16x32_f16(a, buf[k % 10], accx, 0, 0, 0);
                }
            }
#pragma unroll
            for (int r = 0; r < 4; ++r)
                gates[(q * 4 + r) * LDG + ncol] = (f16)(acch[r] + accx[r]);
        }
        __syncthreads();
        int tp1 = t + 1;
        if (tp1 < T_SZ) {
            for (int i = tid; i < 16 * 40; i += 512) {
                int m = i / 40, c8 = i - m * 40;
                int v = capv[m * T_SZ + tp1];
                *(f16x8*)(xbuf + m * LDA + c8 * 8) =
                    *(const f16x8*)(embT + (size_t)v * KP + c8 * 8);
            }
        }
#pragma unroll
        for (int it = 0; it < 10; ++it) {
            int idx = tid + it * 512;
            int m = idx / 320, j = idx - m * 320;
            if (j < H_SZ) {
                const f16* gr = gates + m * LDG;
                float gi = (float)gr[j];
                float gf = (float)gr[GP + j];
                float gg = (float)gr[2 * GP + j];
                float go = (float)gr[3 * GP + j];
                float ii = sigmoid_f(gi);
                float ff = sigmoid_f(gf);
                float gt = tanh_f(gg);
                float oo = sigmoid_f(go);
                float cn = ff * creg[it] + ii * gt;
                creg[it] = cn;
                float hh = oo * tanh_f(cn);
                hbuf[m * LDA + j] = (f16)hh;
                if (t == lens[m] - 1) hlast[(size_t)(b0 + m) * GP + j] = hh;
            }
        }
        __syncthreads();
    }
}

// kC: out[row][cl] = hlast[row] . Wc[cl] + cls_b[cl]
__global__ void kC(const float* __restrict__ hlast, const float* __restrict__ Wc,
                   const float* __restrict__ cls_b, float* __restrict__ out) {
    int row = blockIdx.x, lane = threadIdx.x;
    const float* h = hlast + (size_t)row * GP;
    float s0 = 0.f, s1 = 0.f;
    for (int j = lane; j < H_SZ; j += 64) {
        float hv = h[j];
        s0 += hv * Wc[j];
        s1 += hv * Wc[GP + j];
    }
    for (int off = 32; off; off >>= 1) {
        s0 += __shfl_down(s0, off);
        s1 += __shfl_down(s1, off);
    }
    if (lane == 0) {
        out[row * 2 + 0] = s0 + cls_b[0];
        out[row * 2 + 1] = s1 + cls_b[1];
    }
}

extern "C" void kernel_launch(void* const* d_in, const int* in_sizes, int n_in,
                              void* d_out, int out_size, void* d_ws, size_t ws_size,
                              hipStream_t stream) {
    const int*   cap     = (const int*)d_in[0];
    const int*   cap_len = (const int*)d_in[1];
    const float* embed_w = (const float*)d_in[2];
    const float* W_ih    = (const float*)d_in[3];
    const float* W_hh    = (const float*)d_in[4];
    const float* b_ih    = (const float*)d_in[5];
    const float* b_hh    = (const float*)d_in[6];
    const float* cls_v   = (const float*)d_in[7];
    const float* cls_g   = (const float*)d_in[8];
    const float* cls_b   = (const float*)d_in[9];
    float* out = (float*)d_out;

    char* w = (char*)d_ws;
    size_t off = 0;
    auto alloc = [&](size_t bytes) -> void* {
        void* p = w + off;
        off += (bytes + 255) & ~(size_t)255;
        return p;
    };
    f16*   embT  = (f16*)alloc((size_t)VOCAB * KP * sizeof(f16));      // 6.4 MB
    f16*   Wpk   = (f16*)alloc((size_t)1520 * 64 * 8 * sizeof(f16));   // 1.56 MB
    f16*   WgS   = (f16*)alloc((size_t)800 * 64 * 8 * sizeof(f16));    // 819 KB (w/ slack)
    float* biasp = (float*)alloc((size_t)G4 * sizeof(float));
    float* Wc    = (float*)alloc((size_t)2 * GP * sizeof(float));
    float* hlast = (float*)alloc((size_t)B_SZ * GP * sizeof(float));   // 5.0 MB
    f16*   embX  = (f16*)(w + off);                                    // 24.3 MB f16 [V][GP][4]
    size_t need_split = off + ((size_t)VOCAB * GP * 4 * sizeof(f16) + 255);
    bool split = (ws_size >= need_split);          // deterministic per run

    kP0<<<VOCAB, KP, 0, stream>>>(embed_w, embT);
    kPW2<<<1520, 64, 0, stream>>>(W_ih, W_hh, b_ih, b_hh, Wpk, biasp);
    kP2<<<1, 64, 0, stream>>>(cls_v, cls_g, Wc);
    if (split) {
        kPW4<<<800, 64, 0, stream>>>(W_hh, WgS);
        kX2<<<VOCAB / 16, 512, 0, stream>>>(embT, Wpk, biasp, embX);
        kR12<<<NBLK, 512, 0, stream>>>(cap, cap_len, embX, WgS, hlast);
    } else {
        static const int smem_r8 = 67072 + 64;
        (void)hipFuncSetAttribute((const void*)kR8,
                                  hipFuncAttributeMaxDynamicSharedMemorySize, smem_r8);
        kR8<<<B_SZ / 16, 512, smem_r8, stream>>>(cap, cap_len, embT, Wpk, biasp, hlast);
    }
    kC<<<B_SZ, 64, 0, stream>>>(hlast, Wc, cls_b, out);
}

// Round 14
// 421.625 us; speedup vs baseline: 1.9783x; 1.2037x over previous
//
#include <hip/hip_runtime.h>
#include <hip/hip_fp16.h>

typedef _Float16 f16;
typedef _Float16 f16x4 __attribute__((ext_vector_type(4)));
typedef _Float16 f16x8 __attribute__((ext_vector_type(8)));
typedef float f32x4 __attribute__((ext_vector_type(4)));

#define B_SZ   4096
#define T_SZ   32
#define VOCAB  10000
#define E_SZ   300
#define H_SZ   300
#define KP     320          // embT row width (10x32)
#define GP     304          // per-gate padded N (19x16)
#define G4     1216         // 4*GP
#define LDA    328          // hbuf row stride f16
#define LDG    1224         // kR8 gates row stride f16
#define LDX    1224         // xst row stride f16 ([j][4] = 1216 + 8 pad)
#define LDC    308          // cbuf row stride f32
#define ROWS   16
#define NBLK   (B_SZ/ROWS)  // 256 blocks -> 1 per CU

__device__ __forceinline__ float sigmoid_f(float x) {
    return 1.f / (1.f + __expf(-x));
}
__device__ __forceinline__ float tanh_f(float x) {
    return 2.f / (1.f + __expf(-2.f * x)) - 1.f;
}

// P0: embed_w f32 [V][300] -> embT f16 [V][320] zero-padded
__global__ void kP0(const float* __restrict__ ew, f16* __restrict__ embT) {
    int v = blockIdx.x, k = threadIdx.x;           // 320 threads
    embT[(size_t)v * KP + k] = (k < E_SZ) ? (f16)ew[(size_t)v * E_SZ + k] : (f16)0.f;
}

// kPW2: fused-stream packing (for kX2 / kR8): block (gate,nt,k20), 1 KB each.
__global__ void kPW2(const float* __restrict__ wih, const float* __restrict__ whh,
                     const float* __restrict__ bih, const float* __restrict__ bhh,
                     f16* __restrict__ Wpk, float* __restrict__ biasp) {
    int bid = blockIdx.x;                          // 0..1519 = (gate*19+nt)*20+k
    int lane = threadIdx.x;                        // 64
    int k = bid % 20, ntg = bid / 20;
    int nt = ntg % 19, gate = ntg / 19;
    int c = lane & 15, q = lane >> 4;
    int j = nt * 16 + c;
    int src = gate * H_SZ + j;
    f16 vals[8];
#pragma unroll
    for (int jj = 0; jj < 8; ++jj) {
        int kk = k * 32 + q * 8 + jj;
        float v = 0.f;
        if (j < H_SZ) {
            if (kk < KP) { if (kk < H_SZ) v = whh[(size_t)src * H_SZ + kk]; }
            else { int kx = kk - KP; if (kx < E_SZ) v = wih[(size_t)src * E_SZ + kx]; }
        }
        vals[jj] = (f16)v;
    }
    *(f16x8*)(Wpk + ((size_t)bid * 64 + lane) * 8) = *(const f16x8*)vals;
    if (k == 0 && q == 0)
        biasp[gate * GP + j] = (j < H_SZ) ? (bih[src] + bhh[src]) : 0.f;
}

// kPW4: gate-major W_hh-only packing: block (nt, gate, k10), 1 KB each.
// 800 blocks (760 real + 40 zero slack for unconditional prefetch).
__global__ void kPW4(const float* __restrict__ whh, f16* __restrict__ WgS) {
    int bid = blockIdx.x;                          // 0..799
    int lane = threadIdx.x;
    int c = lane & 15, q = lane >> 4;
    f16 vals[8];
    if (bid < 760) {
        int nt = bid / 40, g = (bid % 40) / 10, k = bid % 10;
        int j = nt * 16 + c;
        int src = g * H_SZ + j;
#pragma unroll
        for (int jj = 0; jj < 8; ++jj) {
            int kk = k * 32 + q * 8 + jj;
            float v = (j < H_SZ && kk < H_SZ) ? whh[(size_t)src * H_SZ + kk] : 0.f;
            vals[jj] = (f16)v;
        }
    } else {
#pragma unroll
        for (int jj = 0; jj < 8; ++jj) vals[jj] = (f16)0.f;
    }
    *(f16x8*)(WgS + ((size_t)bid * 64 + lane) * 8) = *(const f16x8*)vals;
}

// P2: weight-normed classifier W = g * v / ||v||  -> Wc f32 [2][GP]
__global__ void kP2(const float* __restrict__ cls_v, const float* __restrict__ cls_g,
                    float* __restrict__ Wc) {
    int lane = threadIdx.x;
    for (int cl = 0; cl < 2; ++cl) {
        float s = 0.f;
        for (int j = lane; j < H_SZ; j += 64) { float v = cls_v[cl * H_SZ + j]; s += v * v; }
        for (int off = 32; off; off >>= 1) s += __shfl_down(s, off);
        float nrm = sqrtf(__shfl(s, 0));
        float scale = cls_g[cl] / nrm;
        for (int j = lane; j < H_SZ; j += 64) Wc[cl * GP + j] = cls_v[cl * H_SZ + j] * scale;
    }
}

// kX2: per-vocab x-gate preacts, gate-interleaved f16:
// embX[v][j][gate] = (W_ih . emb[v] + b_ih + b_hh)[gate*300+j]   (row = 2432 B)
__global__ __launch_bounds__(512, 2)
void kX2(const f16* __restrict__ embT, const f16* __restrict__ Wpk,
         const float* __restrict__ biasp, f16* __restrict__ embX) {
    int tid = threadIdx.x;
    int v0 = blockIdx.x * 16;
    int wave = tid >> 6, lane = tid & 63;
    int c = lane & 15, q = lane >> 4;
    int gate = wave >> 1, half = wave & 1;
    int nt0 = half * 10, ntiles = half ? 9 : 10;
    const f16* wp0 = Wpk + (((size_t)(gate * 19 + nt0) * 20 + 10) * 64 + lane) * 8;
    f16x8 afr[10];
    const f16* arow = embT + (size_t)(v0 + c) * KP + q * 8;
#pragma unroll
    for (int k = 0; k < 10; ++k)
        afr[k] = *(const f16x8*)(arow + k * 32);
    f16x8 buf[10];
#pragma unroll
    for (int s = 0; s < 10; ++s)
        buf[s] = *(const f16x8*)(wp0 + (size_t)s * 512);
#pragma unroll 1
    for (int nt = 0; nt < ntiles - 1; ++nt) {
        int jcol = (nt0 + nt) * 16 + c;
        float bia = biasp[gate * GP + jcol];
        f32x4 acc = {bia, bia, bia, bia};
#pragma unroll
        for (int k = 0; k < 10; ++k) {
            acc = __builtin_amdgcn_mfma_f32_16x16x32_f16(afr[k], buf[k], acc, 0, 0, 0);
            buf[k] = *(const f16x8*)(wp0 + (size_t)(nt * 20 + k + 20) * 512);
        }
#pragma unroll
        for (int r = 0; r < 4; ++r)
            embX[((size_t)(v0 + q * 4 + r) * GP + jcol) * 4 + gate] = (f16)acc[r];
    }
    {
        int nt = ntiles - 1;
        int jcol = (nt0 + nt) * 16 + c;
        float bia = biasp[gate * GP + jcol];
        f32x4 acc = {bia, bia, bia, bia};
#pragma unroll
        for (int k = 0; k < 10; ++k)
            acc = __builtin_amdgcn_mfma_f32_16x16x32_f16(afr[k], buf[k], acc, 0, 0, 0);
#pragma unroll
        for (int r = 0; r < 4; ++r)
            embX[((size_t)(v0 + q * 4 + r) * GP + jcol) * 4 + gate] = (f16)acc[r];
    }
}

// kR13: kR12 + LDS-staged x-preacts. The embX row for step t+1 is copied into a
// double-buffered LDS stage during step t's phase 1 (bulk coalesced 16B chunks,
// full-step latency slack) -> the dependent ~900-cyc HBM gather stall leaves the
// critical path. Gates stay in registers; ONE barrier per step.
__global__ __launch_bounds__(512, 2)
void kR13(const int* __restrict__ cap,
          const int* __restrict__ cap_len,
          const f16* __restrict__ embX,
          const f16* __restrict__ WgS,
          float* __restrict__ hlast) {
    extern __shared__ __align__(16) char smem[];
    f16*   hbufA = (f16*)smem;                           // 2 x 16*LDA = 20992 B
    f16*   xst   = (f16*)(smem + 20992);                 // 2 x 16*LDX*2 = 78336 B
    float* cbuf  = (float*)(smem + 99328);               // 16*LDC*4 = 19712 B
    int*   capv  = (int*)(smem + 119040);                // 2048 B
    int*   lens  = (int*)(smem + 121088);                // 64 B
    int tid = threadIdx.x;
    int b0 = blockIdx.x * ROWS;
    if (tid < ROWS) lens[tid] = cap_len[b0 + tid];
    for (int i = tid; i < ROWS * T_SZ; i += 512) capv[i] = cap[(size_t)b0 * T_SZ + i];
    for (int i = tid; i < 2 * ROWS * LDA; i += 512) hbufA[i] = (f16)0.f;
    for (int i = tid; i < ROWS * LDC; i += 512) cbuf[i] = 0.f;
    __syncthreads();
    // stage x-preacts for t=0 into xst[0] (152 x 16B chunks per row)
    for (int i = tid; i < ROWS * 152; i += 512) {
        int m = i / 152, c8 = i - m * 152;
        int v = capv[m * T_SZ + 0];
        *(f16x8*)(xst + m * LDX + c8 * 8) = *(const f16x8*)(embX + (size_t)v * G4 + c8 * 8);
    }
    __syncthreads();
    int wave = tid >> 6, lane = tid & 63;
    int c = lane & 15, q = lane >> 4;
    int tstart = (wave < 5) ? 2 * wave : 10 + 3 * (wave - 5);   // 19 = 5x2 + 3x3
    int tcnt   = (wave < 5) ? 2 : 3;
    const f16* wp0 = WgS + ((size_t)(tstart * 40) * 64 + lane) * 8;
    int tstop[4];
#pragma unroll
    for (int r = 0; r < 4; ++r) tstop[r] = lens[q * 4 + r] - 1;
    int cur = 0;

    for (int t = 0; t < T_SZ; ++t) {
        const f16* hb = hbufA + cur * (ROWS * LDA);
        f16*       hn = hbufA + (cur ^ 1) * (ROWS * LDA);
        const f16* xc = xst + (t & 1) * (ROWS * LDX);
        f16*       xn = xst + ((t + 1) & 1) * (ROWS * LDX);
        // stage next step's x-preacts FIRST (loads issue early, consumed after barrier)
        int tp1 = t + 1;
        if (tp1 < T_SZ) {
            for (int i = tid; i < ROWS * 152; i += 512) {
                int m = i / 152, c8 = i - m * 152;
                int v = capv[m * T_SZ + tp1];
                *(f16x8*)(xn + m * LDX + c8 * 8) =
                    *(const f16x8*)(embX + (size_t)v * G4 + c8 * 8);
            }
        }
        f16x8 afr[10];
#pragma unroll
        for (int k = 0; k < 10; ++k)
            afr[k] = *(const f16x8*)(hb + c * LDA + k * 32 + q * 8);
        f16x8 buf[10];
#pragma unroll
        for (int s = 0; s < 10; ++s)
            buf[s] = *(const f16x8*)(wp0 + (size_t)s * 512);
#pragma unroll 1
        for (int nt = 0; nt < tcnt; ++nt) {
            int col = (tstart + nt) * 16 + c;
            const f16* wnext = wp0 + (size_t)(nt * 40) * 512;
            f32x4 acc0 = {0.f, 0.f, 0.f, 0.f};
            f32x4 acc1 = {0.f, 0.f, 0.f, 0.f};
            f32x4 acc2 = {0.f, 0.f, 0.f, 0.f};
            f32x4 acc3 = {0.f, 0.f, 0.f, 0.f};
#pragma unroll
            for (int k = 0; k < 10; ++k) {          // gate 0, prefetch gate 1
                acc0 = __builtin_amdgcn_mfma_f32_16x16x32_f16(afr[k], buf[k], acc0, 0, 0, 0);
                buf[k] = *(const f16x8*)(wnext + (size_t)(10 + k) * 512);
            }
#pragma unroll
            for (int k = 0; k < 10; ++k) {          // gate 1, prefetch gate 2
                acc1 = __builtin_amdgcn_mfma_f32_16x16x32_f16(afr[k], buf[k], acc1, 0, 0, 0);
                buf[k] = *(const f16x8*)(wnext + (size_t)(20 + k) * 512);
            }
#pragma unroll
            for (int k = 0; k < 10; ++k) {          // gate 2, prefetch gate 3
                acc2 = __builtin_amdgcn_mfma_f32_16x16x32_f16(afr[k], buf[k], acc2, 0, 0, 0);
                buf[k] = *(const f16x8*)(wnext + (size_t)(30 + k) * 512);
            }
#pragma unroll
            for (int k = 0; k < 10; ++k) {          // gate 3, prefetch next tile g0 (slack-safe)
                acc3 = __builtin_amdgcn_mfma_f32_16x16x32_f16(afr[k], buf[k], acc3, 0, 0, 0);
                buf[k] = *(const f16x8*)(wnext + (size_t)(40 + k) * 512);
            }
            // cell update: rows q*4+r, column col — x-preacts from LDS stage
#pragma unroll
            for (int r = 0; r < 4; ++r) {
                int row = q * 4 + r;
                f16x4 xi = *(const f16x4*)(xc + row * LDX + col * 4);
                float gi = acc0[r] + (float)xi[0];
                float gf = acc1[r] + (float)xi[1];
                float gg = acc2[r] + (float)xi[2];
                float go = acc3[r] + (float)xi[3];
                float ii = sigmoid_f(gi);
                float ff = sigmoid_f(gf);
                float gt = tanh_f(gg);
                float oo = sigmoid_f(go);
                int ci = row * LDC + col;
                float cn = ff * cbuf[ci] + ii * gt;
                cbuf[ci] = cn;
                float hh = oo * tanh_f(cn);
                hn[row * LDA + col] = (f16)hh;
                if (t == tstop[r]) hlast[(size_t)(b0 + row) * GP + col] = hh;
            }
        }
        __syncthreads();
        cur ^= 1;
    }
}

// kR8 (fallback, proven): fused [h|x] recurrence for small-ws runs.
__global__ __launch_bounds__(512, 2)
void kR8(const int* __restrict__ cap,
         const int* __restrict__ cap_len,
         const f16* __restrict__ embT,
         const f16* __restrict__ Wpk,
         const float* __restrict__ biasp,
         float* __restrict__ hlast) {
    extern __shared__ __align__(16) char smem[];
    f16*   hbuf  = (f16*)smem;                          // 10496
    f16*   xbuf  = (f16*)(smem + 10496);                // 10496
    f16*   gates = (f16*)(smem + 20992);                // 39168
    float* biasL = (float*)(smem + 60160);              // 4864
    int*   capv  = (int*)(smem + 65024);                // 2048
    int*   lens  = (int*)(smem + 67072);                // 64
    int tid = threadIdx.x;
    int b0 = blockIdx.x * 16;
    if (tid < 16) lens[tid] = cap_len[b0 + tid];
    for (int i = tid; i < 16 * T_SZ; i += 512) capv[i] = cap[(size_t)b0 * T_SZ + i];
    for (int i = tid; i < 16 * LDA; i += 512) hbuf[i] = (f16)0.f;
    for (int i = tid; i < G4; i += 512) biasL[i] = biasp[i];
    __syncthreads();
    for (int i = tid; i < 16 * 40; i += 512) {
        int m = i / 40, c8 = i - m * 40;
        int v = capv[m * T_SZ + 0];
        *(f16x8*)(xbuf + m * LDA + c8 * 8) = *(const f16x8*)(embT + (size_t)v * KP + c8 * 8);
    }
    __syncthreads();
    int wave = tid >> 6, lane = tid & 63;
    int c = lane & 15, q = lane >> 4;
    int gate = wave >> 1, half = wave & 1;
    int nt0 = half * 10, ntiles = half ? 9 : 10;
    const f16* wp0 = Wpk + ((size_t)((gate * 19 + nt0) * 20) * 64 + lane) * 8;
    const f16* hrow = hbuf + c * LDA + q * 8;
    const f16* xrow = xbuf + c * LDA + q * 8;
    float creg[10];
#pragma unroll
    for (int i = 0; i < 10; ++i) creg[i] = 0.f;

    for (int t = 0; t < T_SZ; ++t) {
        f16x8 afr[10];
#pragma unroll
        for (int k = 0; k < 10; ++k)
            afr[k] = *(const f16x8*)(hrow + k * 32);
        f16x8 buf[10];
#pragma unroll
        for (int s = 0; s < 10; ++s)
            buf[s] = *(const f16x8*)(wp0 + (size_t)s * 512);
#pragma unroll 1
        for (int nt = 0; nt < ntiles - 1; ++nt) {
            int base = nt * 20;
            int ncol = gate * GP + (nt0 + nt) * 16 + c;
            float bia = biasL[ncol];
            f32x4 acch = {bia, bia, bia, bia};
            f32x4 accx = {0.f, 0.f, 0.f, 0.f};
#pragma unroll
            for (int k = 0; k < 20; ++k) {
                if (k < 10) {
                    acch = __builtin_amdgcn_mfma_f32_16x16x32_f16(afr[k], buf[k % 10], acch, 0, 0, 0);
                } else {
                    f16x8 a = *(const f16x8*)(xrow + (k - 10) * 32);
                    accx = __builtin_amdgcn_mfma_f32_16x16x32_f16(a, buf[k % 10], accx, 0, 0, 0);
                }
                buf[k % 10] = *(const f16x8*)(wp0 + (size_t)(base + k + 10) * 512);
            }
#pragma unroll
            for (int r = 0; r < 4; ++r)
                gates[(q * 4 + r) * LDG + ncol] = (f16)(acch[r] + accx[r]);
        }
        {
            int nt = ntiles - 1;
            int base = nt * 20;
            int ncol = gate * GP + (nt0 + nt) * 16 + c;
            float bia = biasL[ncol];
            f32x4 acch = {bia, bia, bia, bia};
            f32x4 accx = {0.f, 0.f, 0.f, 0.f};
#pragma unroll
            for (int k = 0; k < 20; ++k) {
                if (k < 10) {
                    acch = __builtin_amdgcn_mfma_f32_16x16x32_f16(afr[k], buf[k % 10], acch, 0, 0, 0);
                    buf[k % 10] = *(const f16x8*)(wp0 + (size_t)(base + k + 10) * 512);
                } else {
                    f16x8 a = *(const f16x8*)(xrow + (k - 10) * 32);
                    accx = __builtin_amdgcn_mfma_f32_16x16x32_f16(a, buf[k % 10], accx, 0, 0, 0);
                }
            }
#pragma unroll
            for (int r = 0; r < 4; ++r)
                gates[(q * 4 + r) * LDG + ncol] = (f16)(acch[r] + accx[r]);
        }
        __syncthreads();
        int tp1 = t + 1;
        if (tp1 < T_SZ) {
            for (int i = tid; i < 16 * 40; i += 512) {
                int m = i / 40, c8 = i - m * 40;
                int v = capv[m * T_SZ + tp1];
                *(f16x8*)(xbuf + m * LDA + c8 * 8) =
                    *(const f16x8*)(embT + (size_t)v * KP + c8 * 8);
            }
        }
#pragma unroll
        for (int it = 0; it < 10; ++it) {
            int idx = tid + it * 512;
            int m = idx / 320, j = idx - m * 320;
            if (j < H_SZ) {
                const f16* gr = gates + m * LDG;
                float gi = (float)gr[j];
                float gf = (float)gr[GP + j];
                float gg = (float)gr[2 * GP + j];
                float go = (float)gr[3 * GP + j];
                float ii = sigmoid_f(gi);
                float ff = sigmoid_f(gf);
                float gt = tanh_f(gg);
                float oo = sigmoid_f(go);
                float cn = ff * creg[it] + ii * gt;
                creg[it] = cn;
                float hh = oo * tanh_f(cn);
                hbuf[m * LDA + j] = (f16)hh;
                if (t == lens[m] - 1) hlast[(size_t)(b0 + m) * GP + j] = hh;
            }
        }
        __syncthreads();
    }
}

// kC: out[row][cl] = hlast[row] . Wc[cl] + cls_b[cl]
__global__ void kC(const float* __restrict__ hlast, const float* __restrict__ Wc,
                   const float* __restrict__ cls_b, float* __restrict__ out) {
    int row = blockIdx.x, lane = threadIdx.x;
    const float* h = hlast + (size_t)row * GP;
    float s0 = 0.f, s1 = 0.f;
    for (int j = lane; j < H_SZ; j += 64) {
        float hv = h[j];
        s0 += hv * Wc[j];
        s1 += hv * Wc[GP + j];
    }
    for (int off = 32; off; off >>= 1) {
        s0 += __shfl_down(s0, off);
        s1 += __shfl_down(s1, off);
    }
    if (lane == 0) {
        out[row * 2 + 0] = s0 + cls_b[0];
        out[row * 2 + 1] = s1 + cls_b[1];
    }
}

extern "C" void kernel_launch(void* const* d_in, const int* in_sizes, int n_in,
                              void* d_out, int out_size, void* d_ws, size_t ws_size,
                              hipStream_t stream) {
    const int*   cap     = (const int*)d_in[0];
    const int*   cap_len = (const int*)d_in[1];
    const float* embed_w = (const float*)d_in[2];
    const float* W_ih    = (const float*)d_in[3];
    const float* W_hh    = (const float*)d_in[4];
    const float* b_ih    = (const float*)d_in[5];
    const float* b_hh    = (const float*)d_in[6];
    const float* cls_v   = (const float*)d_in[7];
    const float* cls_g   = (const float*)d_in[8];
    const float* cls_b   = (const float*)d_in[9];
    float* out = (float*)d_out;

    char* w = (char*)d_ws;
    size_t off = 0;
    auto alloc = [&](size_t bytes) -> void* {
        void* p = w + off;
        off += (bytes + 255) & ~(size_t)255;
        return p;
    };
    f16*   embT  = (f16*)alloc((size_t)VOCAB * KP * sizeof(f16));      // 6.4 MB
    f16*   Wpk   = (f16*)alloc((size_t)1520 * 64 * 8 * sizeof(f16));   // 1.56 MB
    f16*   WgS   = (f16*)alloc((size_t)800 * 64 * 8 * sizeof(f16));    // 819 KB
    float* biasp = (float*)alloc((size_t)G4 * sizeof(float));
    float* Wc    = (float*)alloc((size_t)2 * GP * sizeof(float));
    float* hlast = (float*)alloc((size_t)B_SZ * GP * sizeof(float));   // 5.0 MB
    f16*   embX  = (f16*)(w + off);                                    // 24.3 MB f16 [V][GP][4]
    size_t need_split = off + ((size_t)VOCAB * GP * 4 * sizeof(f16) + 255);
    bool split = (ws_size >= need_split);          // deterministic per run

    kP0<<<VOCAB, KP, 0, stream>>>(embed_w, embT);
    kPW2<<<1520, 64, 0, stream>>>(W_ih, W_hh, b_ih, b_hh, Wpk, biasp);
    kP2<<<1, 64, 0, stream>>>(cls_v, cls_g, Wc);
    if (split) {
        kPW4<<<800, 64, 0, stream>>>(W_hh, WgS);
        kX2<<<VOCAB / 16, 512, 0, stream>>>(embT, Wpk, biasp, embX);
        // dynamic LDS 121,152 B (<= 160 KB/CU); host-side config, capture-safe
        static const int smem_r13 = 121152;
        (void)hipFuncSetAttribute((const void*)kR13,
                                  hipFuncAttributeMaxDynamicSharedMemorySize, smem_r13);
        kR13<<<NBLK, 512, smem_r13, stream>>>(cap, cap_len, embX, WgS, hlast);
    } else {
        static const int smem_r8 = 67072 + 64;
        (void)hipFuncSetAttribute((const void*)kR8,
                                  hipFuncAttributeMaxDynamicSharedMemorySize, smem_r8);
        kR8<<<B_SZ / 16, 512, smem_r8, stream>>>(cap, cap_len, embT, Wpk, biasp, hlast);
    }
    kC<<<B_SZ, 64, 0, stream>>>(hlast, Wc, cls_b, out);
}